// Round 1
// baseline (35.514 us; speedup 1.0000x reference)
//
#include <hip/hip_runtime.h>

typedef __attribute__((ext_vector_type(8))) short bf16x8;
typedef __attribute__((ext_vector_type(4))) float f32x4;

constexpr int IN_F  = 4096;
constexpr int OUT_F = 11008;
constexpr int NGRP  = 32;   // 4096 / 128

__device__ __forceinline__ short f2bf(float f) {
    unsigned u = __float_as_uint(f);
    u += 0x7FFFu + ((u >> 16) & 1u);   // round-to-nearest-even
    return (short)(u >> 16);
}

// Convert x [8][4096] fp32 -> bf16 in workspace (read once per block later).
__global__ void xprep_kernel(const float* __restrict__ x, short* __restrict__ xb) {
    int i = (blockIdx.x * blockDim.x + threadIdx.x) * 4;
    float4 v = *(const float4*)(x + i);
    short4 r;
    r.x = f2bf(v.x); r.y = f2bf(v.y); r.z = f2bf(v.z); r.w = f2bf(v.w);
    *(short4*)(xb + i) = r;
}

// One block = one 16-wide output-feature tile. 8 waves split K (512 each).
// MFMA 16x16x32 bf16: lane&15 -> A-row m / B-col n(=o), k = 8*(lane>>4)+i (contiguous).
template<bool PRE>
__global__ __launch_bounds__(512)
void qlin_kernel(const int* __restrict__ wq,
                 const float* __restrict__ scales,
                 const float* __restrict__ zeros,
                 const float* __restrict__ bias,
                 const float* __restrict__ xf,
                 const short* __restrict__ xb,
                 float* __restrict__ out)
{
    __shared__ float red[8][64][4];
    const int tid  = threadIdx.x;
    const int wv   = tid >> 6;       // 0..7
    const int lane = tid & 63;
    const int col  = lane & 15;      // B col n (output feature) and A row m
    const int kg   = lane >> 4;      // 0..3 -> k sub-chunk of 8
    const int o0   = blockIdx.x * 16;
    const int orow = o0 + col;

    const int*   wrow  = wq     + (size_t)orow * (IN_F / 2);
    const float* srow  = scales + (size_t)orow * NGRP;
    const float* zrow  = zeros  + (size_t)orow * NGRP;
    const short* xrow  = xb + (size_t)col * IN_F;
    const float* xfrow = xf + (size_t)col * IN_F;
    const bool   mvalid = (col < 8);     // A rows 8..15 are zero padding

    f32x4 acc = {0.f, 0.f, 0.f, 0.f};
    const int kbase = wv * 512;

    #pragma unroll
    for (int gl = 0; gl < 4; ++gl) {
        const int g = (kbase >> 7) + gl;       // quant group (128 k) index
        const float s = srow[g];
        const float z = zrow[g];
        #pragma unroll
        for (int t = 0; t < 4; ++t) {
            const int k0   = kbase + gl * 128 + t * 32;  // k-tile start (whole tile in group g)
            const int ksub = k0 + kg * 8;                // this lane's 8 k's

            // B fragment: 4 int32, each holds one byte = 2 nibbles (low = even k)
            int4 q = *(const int4*)(wrow + (ksub >> 1));
            bf16x8 bfr;
            bfr[0] = f2bf((float)( q.x       & 15) * s + z);
            bfr[1] = f2bf((float)((q.x >> 4) & 15) * s + z);
            bfr[2] = f2bf((float)( q.y       & 15) * s + z);
            bfr[3] = f2bf((float)((q.y >> 4) & 15) * s + z);
            bfr[4] = f2bf((float)( q.z       & 15) * s + z);
            bfr[5] = f2bf((float)((q.z >> 4) & 15) * s + z);
            bfr[6] = f2bf((float)( q.w       & 15) * s + z);
            bfr[7] = f2bf((float)((q.w >> 4) & 15) * s + z);

            // A fragment
            bf16x8 afr = {0, 0, 0, 0, 0, 0, 0, 0};
            if (mvalid) {
                if constexpr (PRE) {
                    afr = *(const bf16x8*)(xrow + ksub);
                } else {
                    float4 a0 = *(const float4*)(xfrow + ksub);
                    float4 a1 = *(const float4*)(xfrow + ksub + 4);
                    afr[0] = f2bf(a0.x); afr[1] = f2bf(a0.y);
                    afr[2] = f2bf(a0.z); afr[3] = f2bf(a0.w);
                    afr[4] = f2bf(a1.x); afr[5] = f2bf(a1.y);
                    afr[6] = f2bf(a1.z); afr[7] = f2bf(a1.w);
                }
            }

            acc = __builtin_amdgcn_mfma_f32_16x16x32_bf16(afr, bfr, acc, 0, 0, 0);
        }
    }

    // cross-wave reduction
    *(f32x4*)&red[wv][lane][0] = acc;
    __syncthreads();

    if (tid < 64) {
        f32x4 ssum = *(const f32x4*)&red[0][tid][0];
        #pragma unroll
        for (int w = 1; w < 8; ++w)
            ssum += *(const f32x4*)&red[w][tid][0];
        const int n = tid & 15;
        const float bb = bias[o0 + n];
        const int mbase = (tid >> 4) * 4;   // C/D row = (lane>>4)*4 + reg
        if (mbase < 8) {
            #pragma unroll
            for (int i = 0; i < 4; ++i)
                out[(size_t)(mbase + i) * OUT_F + o0 + n] = ssum[i] + bb;
        }
    }
}

extern "C" void kernel_launch(void* const* d_in, const int* in_sizes, int n_in,
                              void* d_out, int out_size, void* d_ws, size_t ws_size,
                              hipStream_t stream) {
    const float* x  = (const float*)d_in[0];
    const int*   wq = (const int*)d_in[1];
    const float* sc = (const float*)d_in[2];
    const float* zr = (const float*)d_in[3];
    const float* bs = (const float*)d_in[4];
    float* out = (float*)d_out;

    if (ws_size >= (size_t)(8 * IN_F * sizeof(short))) {
        short* xb = (short*)d_ws;
        xprep_kernel<<<(8 * IN_F) / (256 * 4), 256, 0, stream>>>(x, xb);
        qlin_kernel<true><<<OUT_F / 16, 512, 0, stream>>>(wq, sc, zr, bs, x, xb, out);
    } else {
        qlin_kernel<false><<<OUT_F / 16, 512, 0, stream>>>(wq, sc, zr, bs, x, (const short*)d_ws, out);
    }
}

// Round 2
// 31.052 us; speedup vs baseline: 1.1437x; 1.1437x over previous
//
#include <hip/hip_runtime.h>

typedef _Float16 f16;
typedef __attribute__((ext_vector_type(2))) _Float16 f16x2;
typedef __attribute__((ext_vector_type(4))) _Float16 f16x4;
typedef __attribute__((ext_vector_type(8))) _Float16 f16x8;
typedef __attribute__((ext_vector_type(4))) float f32x4;

constexpr int IN_F  = 4096;
constexpr int OUT_F = 11008;
constexpr int NGRP  = 32;   // 4096 / 128

// x [8][4096] fp32 -> f16 in workspace
__global__ void xprep_kernel(const float* __restrict__ x, f16* __restrict__ xh) {
    int i = (blockIdx.x * blockDim.x + threadIdx.x) * 4;
    float4 v = *(const float4*)(x + i);
    f16x4 r = {(f16)v.x, (f16)v.y, (f16)v.z, (f16)v.w};
    *(f16x4*)(xh + i) = r;
}

// dequant one byte-holding int32 (2 nibbles) -> 2 packed f16 weights
__device__ __forceinline__ unsigned dq2(unsigned q, f16x2 sp, f16x2 zp) {
    unsigned t = (((q << 12) | q) & 0x000F000Fu) | 0x64006400u;  // (1024+lo, 1024+hi)
    f16x2 u = __builtin_bit_cast(f16x2, t);
    u = u - (f16x2){(_Float16)1024.0f, (_Float16)1024.0f};       // exact: (lo, hi)
    u = u * sp + zp;                                             // v_pk_fma_f16
    return __builtin_bit_cast(unsigned, u);
}

__device__ __forceinline__ f16x2 bcast(float v) {
    _Float16 h = (_Float16)v;
    return (f16x2){h, h};
}

// One block = one 16-wide output tile. 8 waves split K (512 each = 4 groups).
// MFMA 16x16x32 f16: lane&15 -> A row m / B col n; k = 8*(lane>>4)+i contiguous.
template<bool PRE>
__global__ __launch_bounds__(512)
void qlin_kernel(const int* __restrict__ wq,
                 const float* __restrict__ scales,
                 const float* __restrict__ zeros,
                 const float* __restrict__ bias,
                 const float* __restrict__ xf,
                 const f16* __restrict__ xh,
                 float* __restrict__ out)
{
    __shared__ f32x4 red[8][64];
    const int tid  = threadIdx.x;
    const int wv   = tid >> 6;
    const int lane = tid & 63;
    const int col  = lane & 15;
    const int kg   = lane >> 4;
    const int o0   = blockIdx.x * 16;
    const int orow = o0 + col;
    const bool mvalid = (col < 8);

    const int kbase = wv * 512;
    const int g0    = kbase >> 7;               // wv*4

    // per-wave scales/zeros: 4 contiguous groups, one float4 each
    float4 s4 = *(const float4*)(scales + (size_t)orow * NGRP + g0);
    float4 z4 = *(const float4*)(zeros  + (size_t)orow * NGRP + g0);
    f16x2 sp[4] = {bcast(s4.x), bcast(s4.y), bcast(s4.z), bcast(s4.w)};
    f16x2 zp[4] = {bcast(z4.x), bcast(z4.y), bcast(z4.z), bcast(z4.w)};

    const int* wbase = wq + (size_t)orow * (IN_F / 2) + (kbase >> 1) + kg * 4;
    const f16*   xrow  = xh + (size_t)col * IN_F + kbase + kg * 8;
    const float* xfrow = xf + (size_t)col * IN_F + kbase + kg * 8;

    f32x4 acc = {0.f, 0.f, 0.f, 0.f};

    int4  qb[2][4];
    f16x8 ab[2][4];

    // prologue: load group 0 (4 k-tiles of weights + A-frags)
    #pragma unroll
    for (int t = 0; t < 4; ++t) {
        qb[0][t] = *(const int4*)(wbase + t * 16);
        if (mvalid) {
            if constexpr (PRE) {
                ab[0][t] = *(const f16x8*)(xrow + t * 32);
            } else {
                float4 a0 = *(const float4*)(xfrow + t * 32);
                float4 a1 = *(const float4*)(xfrow + t * 32 + 4);
                ab[0][t] = (f16x8){(f16)a0.x,(f16)a0.y,(f16)a0.z,(f16)a0.w,
                                   (f16)a1.x,(f16)a1.y,(f16)a1.z,(f16)a1.w};
            }
        } else {
            ab[0][t] = (f16x8){0,0,0,0,0,0,0,0};
        }
    }

    #pragma unroll
    for (int gl = 0; gl < 4; ++gl) {
        const int cur = gl & 1, nxt = cur ^ 1;
        if (gl < 3) {
            #pragma unroll
            for (int t = 0; t < 4; ++t) {
                qb[nxt][t] = *(const int4*)(wbase + (gl + 1) * 64 + t * 16);
                if (mvalid) {
                    if constexpr (PRE) {
                        ab[nxt][t] = *(const f16x8*)(xrow + (gl + 1) * 128 + t * 32);
                    } else {
                        float4 a0 = *(const float4*)(xfrow + (gl + 1) * 128 + t * 32);
                        float4 a1 = *(const float4*)(xfrow + (gl + 1) * 128 + t * 32 + 4);
                        ab[nxt][t] = (f16x8){(f16)a0.x,(f16)a0.y,(f16)a0.z,(f16)a0.w,
                                             (f16)a1.x,(f16)a1.y,(f16)a1.z,(f16)a1.w};
                    }
                } else {
                    ab[nxt][t] = (f16x8){0,0,0,0,0,0,0,0};
                }
            }
        }
        const f16x2 s2 = sp[gl], z2 = zp[gl];
        #pragma unroll
        for (int t = 0; t < 4; ++t) {
            const int4 q = qb[cur][t];
            unsigned b0 = dq2((unsigned)q.x, s2, z2);
            unsigned b1 = dq2((unsigned)q.y, s2, z2);
            unsigned b2 = dq2((unsigned)q.z, s2, z2);
            unsigned b3 = dq2((unsigned)q.w, s2, z2);
            typedef __attribute__((ext_vector_type(4))) unsigned u32x4;
            u32x4 bw = {b0, b1, b2, b3};
            f16x8 bfr = __builtin_bit_cast(f16x8, bw);
            acc = __builtin_amdgcn_mfma_f32_16x16x32_f16(ab[cur][t], bfr, acc, 0, 0, 0);
        }
    }

    red[wv][lane] = acc;
    __syncthreads();

    if (tid < 64) {
        f32x4 ssum = red[0][tid];
        #pragma unroll
        for (int w = 1; w < 8; ++w) ssum += red[w][tid];
        const int n = tid & 15;
        const float bb = bias[o0 + n];
        const int mbase = (tid >> 4) * 4;   // C/D row = (lane>>4)*4 + reg
        if (mbase < 8) {
            #pragma unroll
            for (int i = 0; i < 4; ++i)
                out[(size_t)(mbase + i) * OUT_F + o0 + n] = ssum[i] + bb;
        }
    }
}

extern "C" void kernel_launch(void* const* d_in, const int* in_sizes, int n_in,
                              void* d_out, int out_size, void* d_ws, size_t ws_size,
                              hipStream_t stream) {
    const float* x  = (const float*)d_in[0];
    const int*   wq = (const int*)d_in[1];
    const float* sc = (const float*)d_in[2];
    const float* zr = (const float*)d_in[3];
    const float* bs = (const float*)d_in[4];
    float* out = (float*)d_out;

    if (ws_size >= (size_t)(8 * IN_F * sizeof(f16))) {
        f16* xh = (f16*)d_ws;
        xprep_kernel<<<(8 * IN_F) / (256 * 4), 256, 0, stream>>>(x, xh);
        qlin_kernel<true><<<OUT_F / 16, 512, 0, stream>>>(wq, sc, zr, bs, x, xh, out);
    } else {
        qlin_kernel<false><<<OUT_F / 16, 512, 0, stream>>>(wq, sc, zr, bs, x, (const f16*)d_ws, out);
    }
}